// Round 7
// baseline (652.699 us; speedup 1.0000x reference)
//
#include <hip/hip_runtime.h>
#include <cstdint>
#include <cstddef>

#define NFEAT 128
#define TGRAPH 10
#define NGRAPHS 512
#define BN_EPS 1e-5f
#define BIN_CHUNK 2048
#define GSPAN 8    // max graphs a 128-row tile can span
#define TSTR 24    // c_tile row stride in shorts: 48B rows, 16B-aligned, 2-way banks (free)

typedef __attribute__((ext_vector_type(8))) short bf16x8;
typedef __attribute__((ext_vector_type(4))) float f32x4;
typedef __attribute__((ext_vector_type(2))) float f32x2;

__device__ __forceinline__ float bf2f(short s) {
    union { unsigned u; float f; } c;
    c.u = ((unsigned)(unsigned short)s) << 16;
    return c.f;
}
__device__ __forceinline__ short f2bf(float f) {
    union { float f; unsigned u; } c;
    c.f = f;
    unsigned u = c.u;
    return (short)((u + 0x7fffu + ((u >> 16) & 1u)) >> 16);
}
// HW packed f32->bf16 RTNE (guide T12: no builtin on gfx950, inline asm)
__device__ __forceinline__ unsigned cvt_pk_bf16(float lo, float hi) {
    unsigned r;
    asm("v_cvt_pk_bf16_f32 %0, %1, %2" : "=v"(r) : "v"(lo), "v"(hi));
    return r;
}
// packed accumulate: both bf16 halves of dword v -> v_pk_add_f32
__device__ __forceinline__ void accp(f32x2& a, unsigned v) {
    union { unsigned u; float f; } lo, hi;
    lo.u = v << 16;
    hi.u = v & 0xffff0000u;
    f32x2 t;
    t[0] = lo.f;
    t[1] = hi.f;
    a += t;
}

// A-frag memory layout (shorts): buffer of 16-row tiles; element (row, k) lives at
//   ((row>>4)*4 + (k>>5))*512 + (((k>>3)&3)*16 + (row&15))*8 + (k&7)

// ---------------- CSR build, bucket-local (bucket = dst>>9, <=256 buckets) ----------------
__global__ void k_bucket_scan(const int* __restrict__ bhist, int* __restrict__ bbase,
                              int* __restrict__ cur256, int E) {
    __shared__ int s[256];
    int t = threadIdx.x;
    int v = bhist[t];
    s[t] = v;
    __syncthreads();
    for (int off = 1; off < 256; off <<= 1) {
        int x = 0;
        if (t >= off) x = s[t - off];
        __syncthreads();
        if (t >= off) s[t] += x;
        __syncthreads();
    }
    int excl = s[t] - v;
    bbase[t] = excl;
    cur256[t] = excl;
    if (t == 255) bbase[256] = E;
}

__global__ __launch_bounds__(256) void k_bin_scatter(const int* __restrict__ src,
                                                     const int* __restrict__ dst,
                                                     int* __restrict__ cur256,
                                                     int2* __restrict__ binned, int E) {
    __shared__ int hist[256];
    __shared__ int base[256];
    int t = threadIdx.x;
    int e0 = blockIdx.x * BIN_CHUNK;
    int e1 = min(e0 + BIN_CHUNK, E);
    hist[t] = 0;
    __syncthreads();
    for (int e = e0 + t; e < e1; e += 256) {
        int b = dst[e] >> 9;
        atomicAdd(&hist[b], 1);
    }
    __syncthreads();
    int c = hist[t];
    if (c > 0) base[t] = atomicAdd(&cur256[t], c);
    __syncthreads();
    hist[t] = 0;
    __syncthreads();
    for (int e = e0 + t; e < e1; e += 256) {
        int d = dst[e];
        int b = d >> 9;
        int loc = atomicAdd(&hist[b], 1);
        binned[base[b] + loc] = make_int2(src[e], d);
    }
}

__global__ __launch_bounds__(512) void k_bucket_csr(const int2* __restrict__ binned,
                                                    const int* __restrict__ bbase,
                                                    int* __restrict__ rowptr,
                                                    int* __restrict__ adj,
                                                    int N, int E, int nb) {
    __shared__ int deg[512];
    __shared__ int cur[512];
    int b = blockIdx.x;
    int t = threadIdx.x;
    int e0 = bbase[b], e1 = bbase[b + 1];
    deg[t] = 0;
    __syncthreads();
    for (int e = e0 + t; e < e1; e += 512)
        atomicAdd(&deg[binned[e].y & 511], 1);
    __syncthreads();
    int v = deg[t];
    for (int off = 1; off < 512; off <<= 1) {
        int x = 0;
        if (t >= off) x = deg[t - off];
        __syncthreads();
        if (t >= off) deg[t] += x;
        __syncthreads();
    }
    int excl = deg[t] - v;
    cur[t] = excl;
    int node = b * 512 + t;
    if (node < N) rowptr[node] = e0 + excl;
    if (b == nb - 1 && t == 0) rowptr[N] = E;
    __syncthreads();
    for (int e = e0 + t; e < e1; e += 512) {
        int2 p = binned[e];
        int loc = atomicAdd(&cur[p.y & 511], 1);
        adj[e0 + loc] = p.x;
    }
}

// ---------------- merged: bucket histogram + fp32->bf16 convert + weight frag prep -------
__global__ __launch_bounds__(256) void k_prep_hist(const int* __restrict__ dst,
                                                   int* __restrict__ bhist, int E, int hb,
                                                   const float* __restrict__ x,
                                                   short* __restrict__ xbf,
                                                   const float* __restrict__ W0,
                                                   const float* __restrict__ W1,
                                                   const float* __restrict__ W2,
                                                   const float* __restrict__ W3,
                                                   short* __restrict__ Wf, int n4) {
    int t = threadIdx.x;
    if (blockIdx.x < hb) {
        __shared__ int h[256];
        h[t] = 0;
        __syncthreads();
        for (int e = blockIdx.x * 256 + t; e < E; e += hb * 256)
            atomicAdd(&h[dst[e] >> 9], 1);
        __syncthreads();
        if (h[t]) atomicAdd(&bhist[t], h[t]);
        return;
    }
    int i = (blockIdx.x - hb) * 256 + t;
    if (i < n4) {
        float4 v = ((const float4*)x)[i];
        uint2 o;
        o.x = cvt_pk_bf16(v.x, v.y);
        o.y = cvt_pk_bf16(v.z, v.w);
        ((uint2*)xbf)[i] = o;
    } else {
        int idx = i - n4;
        if (idx < 4 * 16384) {
            int w = idx >> 14, r = idx & 16383;
            int j = r & 7, lane = (r >> 3) & 63, ct = (r >> 9) & 7, kc = r >> 12;
            int k = kc * 32 + (lane >> 4) * 8 + j;
            int n = ct * 16 + (lane & 15);
            const float* W = (w == 0) ? W0 : (w == 1) ? W1 : (w == 2) ? W2 : W3;
            Wf[idx] = f2bf(W[k * NFEAT + n]);
        }
    }
}

// ---------------- aggregation (bf16): PROVEN structure, untouched -----------------------
__global__ __launch_bounds__(256) void k_aggregate_v4(const short* __restrict__ X,
                                                      const int* __restrict__ rowptr,
                                                      const int* __restrict__ adj,
                                                      short* __restrict__ XA, int N) {
    int tid = threadIdx.x;
    int lane = tid & 63;
    int g = lane >> 4;
    int p = lane & 15;
    int wid = (blockIdx.x * blockDim.x + tid) >> 6;
    if (wid >= N) return;
    const uint4* Xv = (const uint4*)X;  // one row = 16 uint4
    f32x2 ac[4];
#pragma unroll
    for (int j = 0; j < 4; j++) ac[j] = (f32x2){0.f, 0.f};
    int r0 = rowptr[wid], r1 = rowptr[wid + 1];
    for (int e = r0; e < r1; e += 16) {
        int ea = e + g, eb = e + 4 + g, ec = e + 8 + g, ed = e + 12 + g;
        uint4 v0 = {0u, 0u, 0u, 0u}, v1 = {0u, 0u, 0u, 0u};
        uint4 v2 = {0u, 0u, 0u, 0u}, v3 = {0u, 0u, 0u, 0u};
        if (ea < r1) v0 = Xv[(size_t)adj[ea] * 16 + p];
        if (eb < r1) v1 = Xv[(size_t)adj[eb] * 16 + p];
        if (ec < r1) v2 = Xv[(size_t)adj[ec] * 16 + p];
        if (ed < r1) v3 = Xv[(size_t)adj[ed] * 16 + p];
        accp(ac[0], v0.x); accp(ac[1], v0.y); accp(ac[2], v0.z); accp(ac[3], v0.w);
        accp(ac[0], v1.x); accp(ac[1], v1.y); accp(ac[2], v1.z); accp(ac[3], v1.w);
        accp(ac[0], v2.x); accp(ac[1], v2.y); accp(ac[2], v2.z); accp(ac[3], v2.w);
        accp(ac[0], v3.x); accp(ac[1], v3.y); accp(ac[2], v3.z); accp(ac[3], v3.w);
    }
#pragma unroll
    for (int j = 0; j < 4; j++) {
        ac[j][0] += __shfl_xor(ac[j][0], 16);
        ac[j][1] += __shfl_xor(ac[j][1], 16);
        ac[j][0] += __shfl_xor(ac[j][0], 32);
        ac[j][1] += __shfl_xor(ac[j][1], 32);
    }
    if (g == 0) {
        uint4 sv = Xv[(size_t)wid * 16 + p];
        accp(ac[0], sv.x); accp(ac[1], sv.y); accp(ac[2], sv.z); accp(ac[3], sv.w);
        uint4 o;
        o.x = cvt_pk_bf16(ac[0][0], ac[0][1]);
        o.y = cvt_pk_bf16(ac[1][0], ac[1][1]);
        o.z = cvt_pk_bf16(ac[2][0], ac[2][1]);
        o.w = cvt_pk_bf16(ac[3][0], ac[3][1]);
        size_t dst = ((size_t)(wid >> 4) * 4 + (p >> 2)) * 512 +
                     (size_t)(((p & 3) * 16 + (wid & 15)) * 8);
        *(uint4*)(XA + dst) = o;
    }
}

// ---------------- fused per-layer GEMM pair: GEMM-a+stats | grid barrier | BN+GEMM-b ----
// Each block handles the SAME tile(s) in both phases -> the 32KB Y intermediate stays in
// LDS (zero HBM round trip); only cross-block data is `stats` (atomics) and the barrier.
// Grid sized to guaranteed residency (occupancy query, __launch_bounds__(256,3));
// overflow tiles (nTiles - grid) use the old global-Y path. A-frags prefetched 8-deep.
template <bool POOLB>
__global__ __launch_bounds__(256, 3) void k_gemm_fused(
    const short* __restrict__ A, const short* __restrict__ Wa,
    const short* __restrict__ Wb, const float* __restrict__ ba,
    const float* __restrict__ bb, float* __restrict__ stats,
    const float* __restrict__ gamma, const float* __restrict__ beta,
    const int* __restrict__ batch, float* __restrict__ pooled,
    short* __restrict__ Y, short* __restrict__ C,
    int* __restrict__ bar, int nTiles, int N) {
    __shared__ float s_aux[256];                         // phase A: stats; phase B: BN coeffs
    __shared__ __align__(16) short ylds[16384];          // 128x128 bf16 Y tile, frag layout
    __shared__ __align__(16) short c_tile[4][32 * TSTR]; // per-wave C staging
    __shared__ float s_pool[GSPAN][NFEAT];
    int tid = threadIdx.x;
    int wave = tid >> 6, lane = tid & 63;
    int quad = lane >> 4, l16 = lane & 15;
    int row2 = lane >> 1, half = lane & 1;

    // ---------------- phase A: Y = ag @ Wa + ba, accumulate BN stats ----------------
    bool lds0 = true;
    for (int t = blockIdx.x; t < nTiles; t += gridDim.x, lds0 = false) {
        int row_base = t * 128 + wave * 32;
        const short* af = A + ((size_t)(t * 8 + wave * 2) * 4) * 512;
        bf16x8 a0[4], a1[4];
#pragma unroll
        for (int kc = 0; kc < 4; ++kc) {
            a0[kc] = *(const bf16x8*)(af + (size_t)kc * 512 + lane * 8);
            a1[kc] = *(const bf16x8*)(af + (size_t)(4 + kc) * 512 + lane * 8);
        }
        s_aux[tid] = 0.f;
        __syncthreads();

        f32x4 acc[2][8];
#pragma unroll
        for (int i = 0; i < 2; i++)
#pragma unroll
            for (int j = 0; j < 8; j++) acc[i][j] = (f32x4){0.f, 0.f, 0.f, 0.f};
#pragma unroll
        for (int kc = 0; kc < 4; ++kc) {
            const short* wp = Wa + ((size_t)(kc * 8) * 64 + lane) * 8;
#pragma unroll
            for (int ct = 0; ct < 8; ++ct) {
                bf16x8 b = *(const bf16x8*)(wp + (size_t)ct * 64 * 8);
                acc[0][ct] = __builtin_amdgcn_mfma_f32_16x16x32_bf16(a0[kc], b, acc[0][ct], 0, 0, 0);
                acc[1][ct] = __builtin_amdgcn_mfma_f32_16x16x32_bf16(a1[kc], b, acc[1][ct], 0, 0, 0);
            }
        }

        short* tile = &c_tile[wave][0];
#pragma unroll
        for (int ct = 0; ct < 8; ++ct) {
            int col = ct * 16 + l16;
            float bv = ba[col];
            float ls = 0.f, ls2 = 0.f;
#pragma unroll
            for (int rt = 0; rt < 2; ++rt) {
                float v[4];
#pragma unroll
                for (int reg = 0; reg < 4; ++reg) {
                    int lrow = rt * 16 + quad * 4 + reg;
                    float x = acc[rt][ct][reg] + bv;
                    if (row_base + lrow < N) { ls += x; ls2 += x * x; }
                    v[reg] = x;
                }
                unsigned p01 = cvt_pk_bf16(v[0], v[1]);
                unsigned p23 = cvt_pk_bf16(v[2], v[3]);
                int lr = rt * 16 + quad * 4;
                tile[lr * TSTR + l16] = (short)p01;
                tile[(lr + 1) * TSTR + l16] = (short)(p01 >> 16);
                tile[(lr + 2) * TSTR + l16] = (short)p23;
                tile[(lr + 3) * TSTR + l16] = (short)(p23 >> 16);
            }
            ls += __shfl_xor(ls, 16);
            ls += __shfl_xor(ls, 32);
            ls2 += __shfl_xor(ls2, 16);
            ls2 += __shfl_xor(ls2, 32);
            if (quad == 0) {
                atomicAdd(&s_aux[col], ls);
                atomicAdd(&s_aux[NFEAT + col], ls2);
            }
            // wave-private tile: same-wave DS ordering suffices, no barrier
            uint4 val = *(const uint4*)(tile + row2 * TSTR + half * 8);
            int lrow2 = wave * 32 + row2;  // block-local row 0..127
            int col0 = ct * 16 + half * 8;
            size_t fa = ((size_t)(lrow2 >> 4) * 4 + (col0 >> 5)) * 512 +
                        (size_t)((((col0 >> 3) & 3) * 16 + (lrow2 & 15)) * 8);
            if (lds0) {
                *(uint4*)(ylds + fa) = val;
            } else {
                int grow = row_base + row2;
                if (grow < N) *(uint4*)(Y + (size_t)t * 16384 + fa) = val;
            }
        }
        __syncthreads();
        if (tid < NFEAT) {
            atomicAdd(&stats[tid], s_aux[tid]);
            atomicAdd(&stats[NFEAT + tid], s_aux[NFEAT + tid]);
        }
        __syncthreads();  // protect s_aux re-zero on next tile
    }

    // ---------------- software grid barrier (all blocks resident by construction) -------
    __threadfence();
    __syncthreads();
    if (tid == 0) {
        __hip_atomic_fetch_add(bar, 1, __ATOMIC_RELEASE, __HIP_MEMORY_SCOPE_AGENT);
        while (__hip_atomic_load(bar, __ATOMIC_ACQUIRE, __HIP_MEMORY_SCOPE_AGENT) < (int)gridDim.x)
            __builtin_amdgcn_s_sleep(8);
    }
    __syncthreads();
    __threadfence();

    // ---------------- BN coefficients (stats complete; agent-scope loads = fresh) -------
    if (tid < NFEAT) {
        float sum = __hip_atomic_load(&stats[tid], __ATOMIC_RELAXED, __HIP_MEMORY_SCOPE_AGENT);
        float sq = __hip_atomic_load(&stats[NFEAT + tid], __ATOMIC_RELAXED, __HIP_MEMORY_SCOPE_AGENT);
        float mean = sum / (float)N;
        float var = sq / (float)N - mean * mean;
        float inv = rsqrtf(var + BN_EPS);
        float sc = gamma[tid] * inv;
        s_aux[tid] = sc;
        s_aux[NFEAT + tid] = beta[tid] - mean * sc;
    }
    __syncthreads();

    // ---------------- phase B: out = relu(BN(Y)) @ Wb + bb  (store or pool) -------------
    lds0 = true;
    for (int t = blockIdx.x; t < nTiles; t += gridDim.x, lds0 = false) {
        int row_base = t * 128 + wave * 32;
        bf16x8 a0[4], a1[4];
        if (lds0) {
            const short* af = ylds + (size_t)(wave * 2 * 4) * 512;
#pragma unroll
            for (int kc = 0; kc < 4; ++kc) {
                a0[kc] = *(const bf16x8*)(af + (size_t)kc * 512 + lane * 8);
                a1[kc] = *(const bf16x8*)(af + (size_t)(4 + kc) * 512 + lane * 8);
            }
        } else {
            const short* af = Y + (size_t)t * 16384 + (size_t)(wave * 2 * 4) * 512;
#pragma unroll
            for (int kc = 0; kc < 4; ++kc) {
                a0[kc] = *(const bf16x8*)(af + (size_t)kc * 512 + lane * 8);
                a1[kc] = *(const bf16x8*)(af + (size_t)(4 + kc) * 512 + lane * 8);
            }
        }
        int gbase = 0;
        if constexpr (POOLB) {
            gbase = batch[t * 128];
            for (int i = tid; i < GSPAN * NFEAT; i += 256) s_pool[i >> 7][i & 127] = 0.f;
            __syncthreads();
        }

        f32x4 acc[2][8];
#pragma unroll
        for (int i = 0; i < 2; i++)
#pragma unroll
            for (int j = 0; j < 8; j++) acc[i][j] = (f32x4){0.f, 0.f, 0.f, 0.f};
#pragma unroll
        for (int kc = 0; kc < 4; ++kc) {
            int koff = kc * 32 + quad * 8;
            union { bf16x8 v; unsigned u[4]; } r0, r1;
#pragma unroll
            for (int h = 0; h < 4; ++h) {
                float sca = s_aux[koff + 2 * h];
                float scb = s_aux[koff + 2 * h + 1];
                float sha = s_aux[NFEAT + koff + 2 * h];
                float shb = s_aux[NFEAT + koff + 2 * h + 1];
                float x0 = fmaxf(bf2f(a0[kc][2 * h]) * sca + sha, 0.f);
                float x1 = fmaxf(bf2f(a0[kc][2 * h + 1]) * scb + shb, 0.f);
                float y0 = fmaxf(bf2f(a1[kc][2 * h]) * sca + sha, 0.f);
                float y1 = fmaxf(bf2f(a1[kc][2 * h + 1]) * scb + shb, 0.f);
                r0.u[h] = cvt_pk_bf16(x0, x1);
                r1.u[h] = cvt_pk_bf16(y0, y1);
            }
            const short* wp = Wb + ((size_t)(kc * 8) * 64 + lane) * 8;
#pragma unroll
            for (int ct = 0; ct < 8; ++ct) {
                bf16x8 b = *(const bf16x8*)(wp + (size_t)ct * 64 * 8);
                acc[0][ct] = __builtin_amdgcn_mfma_f32_16x16x32_bf16(r0.v, b, acc[0][ct], 0, 0, 0);
                acc[1][ct] = __builtin_amdgcn_mfma_f32_16x16x32_bf16(r1.v, b, acc[1][ct], 0, 0, 0);
            }
        }

        int dg[8];
        if constexpr (POOLB) {
#pragma unroll
            for (int rt = 0; rt < 2; ++rt)
#pragma unroll
                for (int reg = 0; reg < 4; ++reg) {
                    int row = row_base + rt * 16 + quad * 4 + reg;
                    dg[rt * 4 + reg] = (row < N) ? (batch[row] - gbase) : -1;
                }
        }

        short* tile = &c_tile[wave][0];
#pragma unroll
        for (int ct = 0; ct < 8; ++ct) {
            int col = ct * 16 + l16;
            float bv = bb[col];
            int cg = -1;
            float ps = 0.f;
#pragma unroll
            for (int rt = 0; rt < 2; ++rt) {
                float v[4];
#pragma unroll
                for (int reg = 0; reg < 4; ++reg) {
                    float x = fmaxf(acc[rt][ct][reg] + bv, 0.f);
                    if constexpr (POOLB) {
                        int d = dg[rt * 4 + reg];
                        if (d != cg) {
                            if (cg >= 0) atomicAdd(&s_pool[cg & (GSPAN - 1)][col], ps);
                            cg = d; ps = 0.f;
                        }
                        if (d >= 0) ps += x;
                    }
                    v[reg] = x;
                }
                if constexpr (!POOLB) {
                    unsigned p01 = cvt_pk_bf16(v[0], v[1]);
                    unsigned p23 = cvt_pk_bf16(v[2], v[3]);
                    int lr = rt * 16 + quad * 4;
                    tile[lr * TSTR + l16] = (short)p01;
                    tile[(lr + 1) * TSTR + l16] = (short)(p01 >> 16);
                    tile[(lr + 2) * TSTR + l16] = (short)p23;
                    tile[(lr + 3) * TSTR + l16] = (short)(p23 >> 16);
                }
            }
            if constexpr (POOLB) {
                if (cg >= 0) atomicAdd(&s_pool[cg & (GSPAN - 1)][col], ps);
            } else {
                uint4 val = *(const uint4*)(tile + row2 * TSTR + half * 8);
                int grow = row_base + row2;
                if (grow < N) {
                    int col0 = ct * 16 + half * 8;
                    *(uint4*)(C + (size_t)grow * NFEAT + col0) = val;
                }
            }
        }
        if constexpr (POOLB) {
            __syncthreads();
            for (int i = tid; i < GSPAN * NFEAT; i += 256) {
                float v = s_pool[i >> 7][i & 127];
                if (v != 0.f) {
                    int gg = gbase + (i >> 7);
                    if (gg < NGRAPHS) atomicAdd(&pooled[gg * NFEAT + (i & 127)], v);
                }
            }
        }
    }
}

__global__ void k_final(const float* __restrict__ pooled, const float* __restrict__ Wl,
                        const float* __restrict__ bl, float* __restrict__ out) {
    int idx = blockIdx.x * blockDim.x + threadIdx.x;
    if (idx >= NGRAPHS * TGRAPH) return;
    int g = idx / TGRAPH, t = idx % TGRAPH;
    const float* p = pooled + (size_t)g * NFEAT;
    float acc = bl[t];
#pragma unroll 16
    for (int k = 0; k < NFEAT; ++k) acc += p[k] * Wl[k * TGRAPH + t];
    out[idx] = acc;
}

extern "C" void kernel_launch(void* const* d_in, const int* in_sizes, int n_in,
                              void* d_out, int out_size, void* d_ws, size_t ws_size,
                              hipStream_t stream) {
    const float* x = (const float*)d_in[0];
    const int* ei = (const int*)d_in[1];
    const int* batch = (const int*)d_in[2];
    const float* W1a = (const float*)d_in[3];
    const float* b1a = (const float*)d_in[4];
    const float* g1 = (const float*)d_in[5];
    const float* bt1 = (const float*)d_in[6];
    const float* W1b = (const float*)d_in[7];
    const float* b1b = (const float*)d_in[8];
    const float* W2a = (const float*)d_in[9];
    const float* b2a = (const float*)d_in[10];
    const float* g2 = (const float*)d_in[11];
    const float* bt2 = (const float*)d_in[12];
    const float* W2b = (const float*)d_in[13];
    const float* b2b = (const float*)d_in[14];
    const float* Wl = (const float*)d_in[15];
    const float* bl = (const float*)d_in[16];
    float* out = (float*)d_out;

    int N = in_sizes[2];
    int E = in_sizes[1] / 2;
    int nb = (N + 511) >> 9;
    const int* src = ei;
    const int* dst = ei + E;

    int nTiles = (N + 127) / 128;
    int padRows = nTiles * 128;

    // residency-guaranteed grid for the fused kernels (software grid barrier)
    int occ1 = 0, occ2 = 0;
    hipOccupancyMaxActiveBlocksPerMultiprocessor(&occ1, k_gemm_fused<false>, 256, 0);
    hipOccupancyMaxActiveBlocksPerMultiprocessor(&occ2, k_gemm_fused<true>, 256, 0);
    int occ = occ1 < occ2 ? occ1 : occ2;
    if (occ < 1) occ = 1;
    if (occ > 3) occ = 3;
    int G = occ * 256;
    if (G > nTiles) G = nTiles;

    char* ws = (char*)d_ws;
    size_t off = 0;
    auto alloc = [&](size_t bytes) -> void* {
        void* p = ws + off;
        off = (off + bytes + 255) & ~(size_t)255;
        return p;
    };
    short* xbf = (short*)alloc((size_t)N * NFEAT * 2);        // row-major (gather input)
    short* ag = (short*)alloc((size_t)padRows * NFEAT * 2);   // frag layout
    short* ybf = (short*)alloc((size_t)padRows * NFEAT * 2);  // frag layout (overflow tiles only)
    short* hbf = (short*)alloc((size_t)N * NFEAT * 2);        // row-major (gather input)
    short* Wf = (short*)alloc((size_t)4 * 16384 * 2);
    int* adj = (int*)alloc((size_t)E * 4);
    int2* binned = (int2*)alloc((size_t)E * 8);
    int* rowptr = (int*)alloc((size_t)(N + 1) * 4);
    int* bbase = (int*)alloc(257 * 4);
    int* cur256 = (int*)alloc(256 * 4);
    // zero-region: bhist + stats1 + stats2 + barriers + pooled
    int* bhist = (int*)alloc(256 * 4);
    float* stats1 = (float*)alloc(256 * 4);
    float* stats2 = (float*)alloc(256 * 4);
    int* bar1 = (int*)alloc(256);
    int* bar2 = (int*)alloc(256);
    float* pooled = (float*)alloc((size_t)NGRAPHS * NFEAT * 4);
    size_t zbytes = (char*)(pooled + (size_t)NGRAPHS * NFEAT) - (char*)bhist;

    hipMemsetAsync(bhist, 0, zbytes, stream);

    // ---- merged hist + dtype prep (one dispatch), then CSR chain ----
    int n4 = N * NFEAT / 4;
    int prepTot = n4 + 4 * 16384;
    int hb = 784;
    k_prep_hist<<<hb + (prepTot + 255) / 256, 256, 0, stream>>>(
        dst, bhist, E, hb, x, xbf, W1a, W1b, W2a, W2b, Wf, n4);
    k_bucket_scan<<<1, 256, 0, stream>>>(bhist, bbase, cur256, E);
    k_bin_scatter<<<(E + BIN_CHUNK - 1) / BIN_CHUNK, 256, 0, stream>>>(src, dst, cur256, binned, E);
    k_bucket_csr<<<nb, 512, 0, stream>>>(binned, bbase, rowptr, adj, N, E, nb);

    int aggBlocks = (N + 3) / 4;  // one wave per node

    // ---- layer 1 ----
    k_aggregate_v4<<<aggBlocks, 256, 0, stream>>>(xbf, rowptr, adj, ag, N);
    k_gemm_fused<false><<<G, 256, 0, stream>>>(ag, Wf + 0 * 16384, Wf + 1 * 16384, b1a, b1b,
                                               stats1, g1, bt1, nullptr, nullptr, ybf, hbf,
                                               bar1, nTiles, N);

    // ---- layer 2 (phase B pools directly) ----
    k_aggregate_v4<<<aggBlocks, 256, 0, stream>>>(hbf, rowptr, adj, ag, N);
    k_gemm_fused<true><<<G, 256, 0, stream>>>(ag, Wf + 2 * 16384, Wf + 3 * 16384, b2a, b2b,
                                              stats2, g2, bt2, batch, pooled, ybf, nullptr,
                                              bar2, nTiles, N);

    // ---- classifier ----
    k_final<<<(NGRAPHS * TGRAPH + 255) / 256, 256, 0, stream>>>(pooled, Wl, bl, out);
}

// Round 8
// 460.464 us; speedup vs baseline: 1.4175x; 1.4175x over previous
//
#include <hip/hip_runtime.h>
#include <cstdint>
#include <cstddef>

#define NFEAT 128
#define TGRAPH 10
#define NGRAPHS 512
#define BN_EPS 1e-5f
#define BIN_CHUNK 2048
#define GSPAN 8    // max graphs a 128-row block can span
#define TSTR 24    // c_tile row stride in shorts: 48B rows, 16B-aligned, 2-way banks (free)

typedef __attribute__((ext_vector_type(8))) short bf16x8;
typedef __attribute__((ext_vector_type(4))) float f32x4;
typedef __attribute__((ext_vector_type(2))) float f32x2;

__device__ __forceinline__ float bf2f(short s) {
    union { unsigned u; float f; } c;
    c.u = ((unsigned)(unsigned short)s) << 16;
    return c.f;
}
__device__ __forceinline__ short f2bf(float f) {
    union { float f; unsigned u; } c;
    c.f = f;
    unsigned u = c.u;
    return (short)((u + 0x7fffu + ((u >> 16) & 1u)) >> 16);
}
// HW packed f32->bf16 RTNE (guide T12: no builtin on gfx950, inline asm)
__device__ __forceinline__ unsigned cvt_pk_bf16(float lo, float hi) {
    unsigned r;
    asm("v_cvt_pk_bf16_f32 %0, %1, %2" : "=v"(r) : "v"(lo), "v"(hi));
    return r;
}
// packed accumulate: both bf16 halves of dword v -> v_pk_add_f32
__device__ __forceinline__ void accp(f32x2& a, unsigned v) {
    union { unsigned u; float f; } lo, hi;
    lo.u = v << 16;
    hi.u = v & 0xffff0000u;
    f32x2 t;
    t[0] = lo.f;
    t[1] = hi.f;
    a += t;
}

// A-frag memory layout (shorts): buffer of 16-row tiles; element (row, k) lives at
//   ((row>>4)*4 + (k>>5))*512 + (((k>>3)&3)*16 + (row&15))*8 + (k&7)

// ---------------- CSR build, bucket-local (bucket = dst>>9, <=256 buckets) ----------------
__global__ void k_bucket_scan(const int* __restrict__ bhist, int* __restrict__ bbase,
                              int* __restrict__ cur256, int E) {
    __shared__ int s[256];
    int t = threadIdx.x;
    int v = bhist[t];
    s[t] = v;
    __syncthreads();
    for (int off = 1; off < 256; off <<= 1) {
        int x = 0;
        if (t >= off) x = s[t - off];
        __syncthreads();
        if (t >= off) s[t] += x;
        __syncthreads();
    }
    int excl = s[t] - v;
    bbase[t] = excl;
    cur256[t] = excl;
    if (t == 255) bbase[256] = E;
}

__global__ __launch_bounds__(256) void k_bin_scatter(const int* __restrict__ src,
                                                     const int* __restrict__ dst,
                                                     int* __restrict__ cur256,
                                                     int2* __restrict__ binned, int E) {
    __shared__ int hist[256];
    __shared__ int base[256];
    int t = threadIdx.x;
    int e0 = blockIdx.x * BIN_CHUNK;
    int e1 = min(e0 + BIN_CHUNK, E);
    hist[t] = 0;
    __syncthreads();
    for (int e = e0 + t; e < e1; e += 256) {
        int b = dst[e] >> 9;
        atomicAdd(&hist[b], 1);
    }
    __syncthreads();
    int c = hist[t];
    if (c > 0) base[t] = atomicAdd(&cur256[t], c);
    __syncthreads();
    hist[t] = 0;
    __syncthreads();
    for (int e = e0 + t; e < e1; e += 256) {
        int d = dst[e];
        int b = d >> 9;
        int loc = atomicAdd(&hist[b], 1);
        binned[base[b] + loc] = make_int2(src[e], d);
    }
}

__global__ __launch_bounds__(512) void k_bucket_csr(const int2* __restrict__ binned,
                                                    const int* __restrict__ bbase,
                                                    int* __restrict__ rowptr,
                                                    int* __restrict__ adj,
                                                    int N, int E, int nb) {
    __shared__ int deg[512];
    __shared__ int cur[512];
    int b = blockIdx.x;
    int t = threadIdx.x;
    int e0 = bbase[b], e1 = bbase[b + 1];
    deg[t] = 0;
    __syncthreads();
    for (int e = e0 + t; e < e1; e += 512)
        atomicAdd(&deg[binned[e].y & 511], 1);
    __syncthreads();
    int v = deg[t];
    for (int off = 1; off < 512; off <<= 1) {
        int x = 0;
        if (t >= off) x = deg[t - off];
        __syncthreads();
        if (t >= off) deg[t] += x;
        __syncthreads();
    }
    int excl = deg[t] - v;
    cur[t] = excl;
    int node = b * 512 + t;
    if (node < N) rowptr[node] = e0 + excl;
    if (b == nb - 1 && t == 0) rowptr[N] = E;
    __syncthreads();
    for (int e = e0 + t; e < e1; e += 512) {
        int2 p = binned[e];
        int loc = atomicAdd(&cur[p.y & 511], 1);
        adj[e0 + loc] = p.x;
    }
}

// ---------------- merged: bucket histogram + fp32->bf16 convert + weight frag prep -------
__global__ __launch_bounds__(256) void k_prep_hist(const int* __restrict__ dst,
                                                   int* __restrict__ bhist, int E, int hb,
                                                   const float* __restrict__ x,
                                                   short* __restrict__ xbf,
                                                   const float* __restrict__ W0,
                                                   const float* __restrict__ W1,
                                                   const float* __restrict__ W2,
                                                   const float* __restrict__ W3,
                                                   short* __restrict__ Wf, int n4) {
    int t = threadIdx.x;
    if (blockIdx.x < hb) {
        __shared__ int h[256];
        h[t] = 0;
        __syncthreads();
        for (int e = blockIdx.x * 256 + t; e < E; e += hb * 256)
            atomicAdd(&h[dst[e] >> 9], 1);
        __syncthreads();
        if (h[t]) atomicAdd(&bhist[t], h[t]);
        return;
    }
    int i = (blockIdx.x - hb) * 256 + t;
    if (i < n4) {
        float4 v = ((const float4*)x)[i];
        uint2 o;
        o.x = cvt_pk_bf16(v.x, v.y);
        o.y = cvt_pk_bf16(v.z, v.w);
        ((uint2*)xbf)[i] = o;
    } else {
        int idx = i - n4;
        if (idx < 4 * 16384) {
            int w = idx >> 14, r = idx & 16383;
            int j = r & 7, lane = (r >> 3) & 63, ct = (r >> 9) & 7, kc = r >> 12;
            int k = kc * 32 + (lane >> 4) * 8 + j;
            int n = ct * 16 + (lane & 15);
            const float* W = (w == 0) ? W0 : (w == 1) ? W1 : (w == 2) ? W2 : W3;
            Wf[idx] = f2bf(W[k * NFEAT + n]);
        }
    }
}

// ---------------- aggregation (bf16): PROVEN structure ----------------------------------
// R7 DIAGNOSTIC: node-range [wbase, wend) so each agg runs as TWO half dispatches
// (~33us each). This un-masks the duration-sorted top-5 counter table: the four
// k_gemm_mfma instantiations + prep/CSR kernels surface with full counters.
// Inner loop byte-identical to the proven 3.38 TB/s version.
__global__ __launch_bounds__(256) void k_aggregate_v4(const short* __restrict__ X,
                                                      const int* __restrict__ rowptr,
                                                      const int* __restrict__ adj,
                                                      short* __restrict__ XA,
                                                      int wbase, int wend) {
    int tid = threadIdx.x;
    int lane = tid & 63;
    int g = lane >> 4;
    int p = lane & 15;
    int wid = wbase + ((blockIdx.x * blockDim.x + tid) >> 6);
    if (wid >= wend) return;
    const uint4* Xv = (const uint4*)X;  // one row = 16 uint4
    f32x2 ac[4];
#pragma unroll
    for (int j = 0; j < 4; j++) ac[j] = (f32x2){0.f, 0.f};
    int r0 = rowptr[wid], r1 = rowptr[wid + 1];
    for (int e = r0; e < r1; e += 16) {
        int ea = e + g, eb = e + 4 + g, ec = e + 8 + g, ed = e + 12 + g;
        uint4 v0 = {0u, 0u, 0u, 0u}, v1 = {0u, 0u, 0u, 0u};
        uint4 v2 = {0u, 0u, 0u, 0u}, v3 = {0u, 0u, 0u, 0u};
        if (ea < r1) v0 = Xv[(size_t)adj[ea] * 16 + p];
        if (eb < r1) v1 = Xv[(size_t)adj[eb] * 16 + p];
        if (ec < r1) v2 = Xv[(size_t)adj[ec] * 16 + p];
        if (ed < r1) v3 = Xv[(size_t)adj[ed] * 16 + p];
        accp(ac[0], v0.x); accp(ac[1], v0.y); accp(ac[2], v0.z); accp(ac[3], v0.w);
        accp(ac[0], v1.x); accp(ac[1], v1.y); accp(ac[2], v1.z); accp(ac[3], v1.w);
        accp(ac[0], v2.x); accp(ac[1], v2.y); accp(ac[2], v2.z); accp(ac[3], v2.w);
        accp(ac[0], v3.x); accp(ac[1], v3.y); accp(ac[2], v3.z); accp(ac[3], v3.w);
    }
#pragma unroll
    for (int j = 0; j < 4; j++) {
        ac[j][0] += __shfl_xor(ac[j][0], 16);
        ac[j][1] += __shfl_xor(ac[j][1], 16);
        ac[j][0] += __shfl_xor(ac[j][0], 32);
        ac[j][1] += __shfl_xor(ac[j][1], 32);
    }
    if (g == 0) {
        uint4 sv = Xv[(size_t)wid * 16 + p];
        accp(ac[0], sv.x); accp(ac[1], sv.y); accp(ac[2], sv.z); accp(ac[3], sv.w);
        uint4 o;
        o.x = cvt_pk_bf16(ac[0][0], ac[0][1]);
        o.y = cvt_pk_bf16(ac[1][0], ac[1][1]);
        o.z = cvt_pk_bf16(ac[2][0], ac[2][1]);
        o.w = cvt_pk_bf16(ac[3][0], ac[3][1]);
        size_t dst = ((size_t)(wid >> 4) * 4 + (p >> 2)) * 512 +
                     (size_t)(((p & 3) * 16 + (wid & 15)) * 8);
        *(uint4*)(XA + dst) = o;
    }
}

// ---------------- MFMA GEMM: frag loads; LDS-transposed wide C stores; opt. fused pool ---
template <bool BN_RELU_IN, bool RELU_OUT, bool STATS, bool FRAG_OUT, bool POOL>
__global__ __launch_bounds__(256) void k_gemm_mfma(const short* __restrict__ A,
                                                   const short* __restrict__ Wf,
                                                   const float* __restrict__ bias,
                                                   float* __restrict__ stats,
                                                   const float* __restrict__ gamma,
                                                   const float* __restrict__ beta,
                                                   const int* __restrict__ batch,
                                                   float* __restrict__ pooled,
                                                   short* __restrict__ C, int N) {
    __shared__ float s_aux[256];           // STATS: sum|sq ; BN: scale|shift
    __shared__ __align__(16) short c_tile[4][32 * TSTR]; // per-wave 32-row C staging
    __shared__ float s_pool[GSPAN][NFEAT];
    int tid = threadIdx.x;
    int wave = tid >> 6, lane = tid & 63;
    int quad = lane >> 4, l16 = lane & 15;
    int row_base = blockIdx.x * 128 + wave * 32;

    int gbase = 0;
    if constexpr (POOL) {
        int first = blockIdx.x * 128;
        gbase = (first < N) ? batch[first] : 0;
        for (int i = tid; i < GSPAN * NFEAT; i += 256) s_pool[i >> 7][i & 127] = 0.f;
    }
    if constexpr (STATS) s_aux[tid] = 0.f;
    if constexpr (BN_RELU_IN) {
        if (tid < NFEAT) {
            float mean = stats[tid] / (float)N;
            float var = stats[NFEAT + tid] / (float)N - mean * mean;
            float inv = rsqrtf(var + BN_EPS);
            float sc = gamma[tid] * inv;
            s_aux[tid] = sc;
            s_aux[NFEAT + tid] = beta[tid] - mean * sc;
        }
    }
    if constexpr (STATS || BN_RELU_IN || POOL) __syncthreads();

    f32x4 acc[2][8];
#pragma unroll
    for (int i = 0; i < 2; i++)
#pragma unroll
        for (int j = 0; j < 8; j++) acc[i][j] = (f32x4){0.f, 0.f, 0.f, 0.f};

    const short* af = A + ((size_t)(blockIdx.x * 8 + wave * 2) * 4) * 512;

#pragma unroll
    for (int kc = 0; kc < 4; ++kc) {
        bf16x8 a0 = *(const bf16x8*)(af + (size_t)kc * 512 + lane * 8);
        bf16x8 a1 = *(const bf16x8*)(af + (size_t)(4 + kc) * 512 + lane * 8);
        if constexpr (BN_RELU_IN) {
            int koff = kc * 32 + quad * 8;
            union { bf16x8 v; unsigned u[4]; } r0, r1;
#pragma unroll
            for (int h = 0; h < 4; ++h) {
                float sca = s_aux[koff + 2 * h];
                float scb = s_aux[koff + 2 * h + 1];
                float sha = s_aux[NFEAT + koff + 2 * h];
                float shb = s_aux[NFEAT + koff + 2 * h + 1];
                float x0 = fmaxf(bf2f(a0[2 * h]) * sca + sha, 0.f);
                float x1 = fmaxf(bf2f(a0[2 * h + 1]) * scb + shb, 0.f);
                float y0 = fmaxf(bf2f(a1[2 * h]) * sca + sha, 0.f);
                float y1 = fmaxf(bf2f(a1[2 * h + 1]) * scb + shb, 0.f);
                r0.u[h] = cvt_pk_bf16(x0, x1);
                r1.u[h] = cvt_pk_bf16(y0, y1);
            }
            a0 = r0.v;
            a1 = r1.v;
        }
        const short* wp = Wf + ((size_t)(kc * 8) * 64 + lane) * 8;
#pragma unroll
        for (int ct = 0; ct < 8; ++ct) {
            bf16x8 b = *(const bf16x8*)(wp + (size_t)ct * 64 * 8);
            acc[0][ct] = __builtin_amdgcn_mfma_f32_16x16x32_bf16(a0, b, acc[0][ct], 0, 0, 0);
            acc[1][ct] = __builtin_amdgcn_mfma_f32_16x16x32_bf16(a1, b, acc[1][ct], 0, 0, 0);
        }
    }

    // graph index per (rt,reg) row, hoisted (POOL only)
    int dg[8];
    if constexpr (POOL) {
#pragma unroll
        for (int rt = 0; rt < 2; ++rt)
#pragma unroll
            for (int reg = 0; reg < 4; ++reg) {
                int row = row_base + rt * 16 + quad * 4 + reg;
                dg[rt * 4 + reg] = (row < N) ? (batch[row] - gbase) : -1;
            }
    }

    // C/D layout: col = ct*16 + l16, local row = rt*16 + quad*4 + reg
    short* tile = &c_tile[wave][0];
    int row2 = lane >> 1, half = lane & 1;
#pragma unroll
    for (int ct = 0; ct < 8; ++ct) {
        int col = ct * 16 + l16;
        float bv = bias[col];
        float ls = 0.f, ls2 = 0.f;
        int cg = -1;
        float ps = 0.f;
#pragma unroll
        for (int rt = 0; rt < 2; ++rt) {
            float v[4];
#pragma unroll
            for (int reg = 0; reg < 4; ++reg) {
                int lrow = rt * 16 + quad * 4 + reg;
                float x = acc[rt][ct][reg] + bv;
                if constexpr (RELU_OUT) x = fmaxf(x, 0.f);
                if constexpr (STATS) {
                    if (row_base + lrow < N) { ls += x; ls2 += x * x; }
                }
                if constexpr (POOL) {
                    int d = dg[rt * 4 + reg];
                    if (d != cg) {
                        if (cg >= 0) atomicAdd(&s_pool[cg & (GSPAN - 1)][col], ps);
                        cg = d; ps = 0.f;
                    }
                    if (d >= 0) ps += x;
                }
                v[reg] = x;
            }
            if constexpr (!POOL) {
                unsigned p01 = cvt_pk_bf16(v[0], v[1]);
                unsigned p23 = cvt_pk_bf16(v[2], v[3]);
                int lr = rt * 16 + quad * 4;
                tile[lr * TSTR + l16] = (short)p01;
                tile[(lr + 1) * TSTR + l16] = (short)(p01 >> 16);
                tile[(lr + 2) * TSTR + l16] = (short)p23;
                tile[(lr + 3) * TSTR + l16] = (short)(p23 >> 16);
            }
        }
        if constexpr (POOL) {
            if (cg >= 0) atomicAdd(&s_pool[cg & (GSPAN - 1)][col], ps);
        }
        if constexpr (STATS) {
            ls += __shfl_xor(ls, 16);
            ls += __shfl_xor(ls, 32);
            ls2 += __shfl_xor(ls2, 16);
            ls2 += __shfl_xor(ls2, 32);
            if (quad == 0) {
                atomicAdd(&s_aux[col], ls);
                atomicAdd(&s_aux[NFEAT + col], ls2);
            }
        }
        if constexpr (!POOL) {
            // wave-private tile: same-wave DS ordering suffices, no barrier
            uint4 val = *(const uint4*)(tile + row2 * TSTR + half * 8);
            int grow = row_base + row2;
            if (grow < N) {
                int col0 = ct * 16 + half * 8;
                if constexpr (FRAG_OUT) {
                    size_t addr = ((size_t)(grow >> 4) * 4 + (col0 >> 5)) * 512 +
                                  (size_t)((((col0 >> 3) & 3) * 16 + (grow & 15)) * 8);
                    *(uint4*)(C + addr) = val;
                } else {
                    *(uint4*)(C + (size_t)grow * NFEAT + col0) = val;
                }
            }
        }
    }

    if constexpr (STATS) {
        __syncthreads();
        if (tid < NFEAT) {
            atomicAdd(&stats[tid], s_aux[tid]);
            atomicAdd(&stats[NFEAT + tid], s_aux[NFEAT + tid]);
        }
    }
    if constexpr (POOL) {
        __syncthreads();
        for (int i = tid; i < GSPAN * NFEAT; i += 256) {
            float v = s_pool[i >> 7][i & 127];
            if (v != 0.f) {
                int gg = gbase + (i >> 7);
                if (gg < NGRAPHS) atomicAdd(&pooled[gg * NFEAT + (i & 127)], v);
            }
        }
    }
}

__global__ void k_final(const float* __restrict__ pooled, const float* __restrict__ Wl,
                        const float* __restrict__ bl, float* __restrict__ out) {
    int idx = blockIdx.x * blockDim.x + threadIdx.x;
    if (idx >= NGRAPHS * TGRAPH) return;
    int g = idx / TGRAPH, t = idx % TGRAPH;
    const float* p = pooled + (size_t)g * NFEAT;
    float acc = bl[t];
#pragma unroll 16
    for (int k = 0; k < NFEAT; ++k) acc += p[k] * Wl[k * TGRAPH + t];
    out[idx] = acc;
}

extern "C" void kernel_launch(void* const* d_in, const int* in_sizes, int n_in,
                              void* d_out, int out_size, void* d_ws, size_t ws_size,
                              hipStream_t stream) {
    const float* x = (const float*)d_in[0];
    const int* ei = (const int*)d_in[1];
    const int* batch = (const int*)d_in[2];
    const float* W1a = (const float*)d_in[3];
    const float* b1a = (const float*)d_in[4];
    const float* g1 = (const float*)d_in[5];
    const float* bt1 = (const float*)d_in[6];
    const float* W1b = (const float*)d_in[7];
    const float* b1b = (const float*)d_in[8];
    const float* W2a = (const float*)d_in[9];
    const float* b2a = (const float*)d_in[10];
    const float* g2 = (const float*)d_in[11];
    const float* bt2 = (const float*)d_in[12];
    const float* W2b = (const float*)d_in[13];
    const float* b2b = (const float*)d_in[14];
    const float* Wl = (const float*)d_in[15];
    const float* bl = (const float*)d_in[16];
    float* out = (float*)d_out;

    int N = in_sizes[2];
    int E = in_sizes[1] / 2;
    int nb = (N + 511) >> 9;
    const int* src = ei;
    const int* dst = ei + E;

    int gemmBlocks = (N + 127) / 128;
    int padRows = gemmBlocks * 128;

    char* ws = (char*)d_ws;
    size_t off = 0;
    auto alloc = [&](size_t bytes) -> void* {
        void* p = ws + off;
        off = (off + bytes + 255) & ~(size_t)255;
        return p;
    };
    short* xbf = (short*)alloc((size_t)N * NFEAT * 2);        // row-major (gather input)
    short* ag = (short*)alloc((size_t)padRows * NFEAT * 2);   // frag layout
    short* ybf = (short*)alloc((size_t)padRows * NFEAT * 2);  // frag layout
    short* hbf = (short*)alloc((size_t)N * NFEAT * 2);        // row-major (gather input)
    short* Wf = (short*)alloc((size_t)4 * 16384 * 2);
    int* adj = (int*)alloc((size_t)E * 4);
    int2* binned = (int2*)alloc((size_t)E * 8);
    int* rowptr = (int*)alloc((size_t)(N + 1) * 4);
    int* bbase = (int*)alloc(257 * 4);
    int* cur256 = (int*)alloc(256 * 4);
    // zero-region: bhist + stats1 + stats2 + pooled
    int* bhist = (int*)alloc(256 * 4);
    float* stats1 = (float*)alloc(256 * 4);
    float* stats2 = (float*)alloc(256 * 4);
    float* pooled = (float*)alloc((size_t)NGRAPHS * NFEAT * 4);
    size_t zbytes = (char*)(pooled + (size_t)NGRAPHS * NFEAT) - (char*)bhist;

    hipMemsetAsync(bhist, 0, zbytes, stream);

    // ---- merged hist + dtype prep (one dispatch), then CSR chain ----
    int n4 = N * NFEAT / 4;
    int prepTot = n4 + 4 * 16384;
    int hb = 784;
    k_prep_hist<<<hb + (prepTot + 255) / 256, 256, 0, stream>>>(
        dst, bhist, E, hb, x, xbf, W1a, W1b, W2a, W2b, Wf, n4);
    k_bucket_scan<<<1, 256, 0, stream>>>(bhist, bbase, cur256, E);
    k_bin_scatter<<<(E + BIN_CHUNK - 1) / BIN_CHUNK, 256, 0, stream>>>(src, dst, cur256, binned, E);
    k_bucket_csr<<<nb, 512, 0, stream>>>(binned, bbase, rowptr, adj, N, E, nb);

    // diagnostic split: each aggregate runs as two half-range dispatches (~33us each)
    // so the GEMM / prep dispatches surface in the duration-sorted counter table.
    int Nh = (N + 1) / 2;
    int aggBlocksA = (Nh + 3) / 4;
    int aggBlocksB = ((N - Nh) + 3) / 4;

    // ---- layer 1 ----
    k_aggregate_v4<<<aggBlocksA, 256, 0, stream>>>(xbf, rowptr, adj, ag, 0, Nh);
    k_aggregate_v4<<<aggBlocksB, 256, 0, stream>>>(xbf, rowptr, adj, ag, Nh, N);
    k_gemm_mfma<false, false, true, true, false><<<gemmBlocks, 256, 0, stream>>>(
        ag, Wf + 0 * 16384, b1a, stats1, nullptr, nullptr, nullptr, nullptr, ybf, N);
    k_gemm_mfma<true, true, false, false, false><<<gemmBlocks, 256, 0, stream>>>(
        ybf, Wf + 1 * 16384, b1b, stats1, g1, bt1, nullptr, nullptr, hbf, N);

    // ---- layer 2 (GEMM-b pools directly) ----
    k_aggregate_v4<<<aggBlocksA, 256, 0, stream>>>(hbf, rowptr, adj, ag, 0, Nh);
    k_aggregate_v4<<<aggBlocksB, 256, 0, stream>>>(hbf, rowptr, adj, ag, Nh, N);
    k_gemm_mfma<false, false, true, true, false><<<gemmBlocks, 256, 0, stream>>>(
        ag, Wf + 2 * 16384, b2a, stats2, nullptr, nullptr, nullptr, nullptr, ybf, N);
    k_gemm_mfma<true, true, false, false, true><<<gemmBlocks, 256, 0, stream>>>(
        ybf, Wf + 3 * 16384, b2b, stats2, g2, bt2, batch, pooled, nullptr, N);

    // ---- classifier ----
    k_final<<<(NGRAPHS * TGRAPH + 255) / 256, 256, 0, stream>>>(pooled, Wl, bl, out);
}